// Round 4
// baseline (165.336 us; speedup 1.0000x reference)
//
#include <hip/hip_runtime.h>
#include <stdint.h>
#include <math.h>

// ===========================================================================
// LegacySpikeGeneratorBinomial — exact JAX threefry2x32 replication.
// Round 4: instruction-count attack on the VALU-issue-bound hot loop.
//  * threefry rotates forced to v_alignbit_b32 (1 op) via
//    __builtin_amdgcn_alignbit — 3 VALU ops per round guaranteed.
//  * decision moved to integer domain: u = m*2^-23 exactly (m = ub>>9), so
//      spike0    <=>  m < ceil(p*2^23)                 (signed cmp)
//      border    <=>  (uint)(m - floor((p-.0054)*2^23)) < 90599
//    per-draw epilogue = xor, shift, sub, cmp+addc, cmp  (6 ops).
//  * queue stores raw ub; cold path reconstructs u bit-identically and runs
//    the exact (double-log) erfinv chain. Corrections via LDS atomics
//    (commutative ints -> deterministic).
// ===========================================================================

#if defined(__HIP_DEVICE_COMPILE__)
#define ROTL32(x, r) __builtin_amdgcn_alignbit((x), (x), 32 - (r))
#else
#define ROTL32(x, r) (((x) << (r)) | ((x) >> (32 - (r))))
#endif

#define TF_R(r) { x0 += x1; x1 = ROTL32(x1, (r)); x1 ^= x0; }

static __host__ __device__ __forceinline__ void tf2x32(
    uint32_t k0, uint32_t k1, uint32_t x0, uint32_t x1,
    uint32_t& o0, uint32_t& o1) {
  const uint32_t ks2 = k0 ^ k1 ^ 0x1BD11BDAu;
  x0 += k0; x1 += k1;
  TF_R(13) TF_R(15) TF_R(26) TF_R(6)
  x0 += k1; x1 += ks2 + 1u;
  TF_R(17) TF_R(29) TF_R(16) TF_R(24)
  x0 += ks2; x1 += k0 + 2u;
  TF_R(13) TF_R(15) TF_R(26) TF_R(6)
  x0 += k0; x1 += k1 + 3u;
  TF_R(17) TF_R(29) TF_R(16) TF_R(24)
  x0 += k1; x1 += ks2 + 4u;
  TF_R(13) TF_R(15) TF_R(26) TF_R(6)
  x0 += ks2; x1 += k0 + 5u;
  o0 = x0; o1 = x1;
}

// XLA erf_inv f32 Giles polynomial, given w = -log1p(-x*x).
__device__ __forceinline__ float erfinv_poly(float w, float x) {
#pragma clang fp contract(off)
  float pp;
  if (w < 5.0f) {
    const float ww = w - 2.5f;
    pp = 2.81022636e-08f;
    pp = 3.43273939e-07f  + pp * ww;
    pp = -3.5233877e-06f  + pp * ww;
    pp = -4.39150654e-06f + pp * ww;
    pp = 0.00021858087f   + pp * ww;
    pp = -0.00125372503f  + pp * ww;
    pp = -0.00417768164f  + pp * ww;
    pp = 0.246640727f     + pp * ww;
    pp = 1.50140941f      + pp * ww;
  } else {
    const float ww = sqrtf(w) - 3.0f;
    pp = -0.000200214257f;
    pp = 0.000100950558f  + pp * ww;
    pp = 0.00134934322f   + pp * ww;
    pp = -0.00367342844f  + pp * ww;
    pp = 0.00573950773f   + pp * ww;
    pp = -0.0076224613f   + pp * ww;
    pp = 0.00943887047f   + pp * ww;
    pp = 1.00167406f      + pp * ww;
    pp = 2.83297682f      + pp * ww;
  }
  return pp * x;
}

struct Keys {
  uint32_t kn0[2], ku0[2], kn1[2], ku1[2];   // per-step noise/uniform keys
};

// Exact XLA chain: noise draw at counter j with key (k0,k1), decide spike.
__device__ __forceinline__ int noise_spike_exact(
    uint32_t k0, uint32_t k1, uint32_t j, float p, float u) {
#pragma clang fp contract(off)
  uint32_t n1, n2;
  tf2x32(k0, k1, 0u, j, n1, n2);
  const uint32_t nb = n1 ^ n2;
  const float f = __uint_as_float((nb >> 9) | 0x3f800000u) - 1.0f;
  // uniform(lo=-0x1.fffffep-1, hi=1): (hi-lo) folds to exactly 2.0f;
  // lax.max(lo, .) is a no-op since f*2 >= 0.
  const float x = f * 2.0f + (-0x1.fffffep-1f);
  const float xx = x * x;
  const float v = -xx;                       // log1p argument, in (-1, 0]
  float we;
  if (fabsf(v) < 1e-4f) {
    we = -((-0.5f * v + 1.0f) * v);          // XLA EmitLog1p small path
  } else {
    const float arg = v + 1.0f;              // f32-round first (FAdd)
    we = -(float)log((double)arg);           // ~CR f32 log
  }
  const float ze = erfinv_poly(we, x);
  const float nz = 1e-3f * (0x1.6a09e6p+0f * ze);  // stddev * sqrt2 * erfinv
  const float t = (p + nz) - u;              // Add then Sub, no FMA
  return t > 0.0f ? 1 : 0;                   // max(sign(t),0)
}

#define CAP 512
#define BORDER_W 90599u   // ceil(2*0.0054*2^23)+2, conservative

__global__ __launch_bounds__(256) void spike_kernel(
    const float* __restrict__ rates, float* __restrict__ out,
    Keys K, int n) {
  __shared__ int s_cnt;
  __shared__ uint32_t s_ub[CAP];
  __shared__ uint32_t s_owner[CAP];          // (tid << 4) | draw_id
  __shared__ int s_delta[256];

  const int tid = threadIdx.x;
  const int o = blockIdx.x * 256 + tid;

  s_delta[tid] = 0;
  if (tid == 0) s_cnt = 0;
  __syncthreads();

  // Per-element integer decision constants.
  int Mlo = 0, D = 0;
  if (o < n) {
#pragma clang fp contract(off)
    const float p = rates[o] * 1e-4f;                 // f32(1/10000) mul
    const int P = (int)ceilf(p * 8388608.0f);         // exact: *2^23 is exp shift
    Mlo = (int)floorf((p - 0.0054f) * 8388608.0f);    // conservative low edge
    D = P - Mlo;                                      // spike0 <=> t < D
  }

  int count = 0;
  if (o < n) {
#pragma unroll
    for (int i = 0; i < 2; ++i) {
      const uint32_t kuk0 = (i == 0) ? K.ku0[0] : K.ku1[0];
      const uint32_t kuk1 = (i == 0) ? K.ku0[1] : K.ku1[1];
#pragma unroll
      for (int s = 0; s < 5; ++s) {
        const int d = i * 5 + s;             // draw id 0..9
        const uint32_t j = (uint32_t)o + (uint32_t)s * (uint32_t)n;

        uint32_t b1, b2;
        tf2x32(kuk0, kuk1, 0u, j, b1, b2);
        const uint32_t ub = b1 ^ b2;
        const int m = (int)(ub >> 9);        // u = m * 2^-23 exactly
        const int t = m - Mlo;
        count += (t < D) ? 1 : 0;            // spike0 = u < p

        if ((uint32_t)t < BORDER_W) {        // |u-p| possibly < max|noise|
          const int slot = atomicAdd(&s_cnt, 1);
          if (slot < CAP) {
            s_ub[slot] = ub;
            s_owner[slot] = ((uint32_t)tid << 4) | (uint32_t)d;
          } else {
            // overflow fallback (statistically unreachable): exact inline
#pragma clang fp contract(off)
            const float p = rates[o] * 1e-4f;
            const float u =
                __uint_as_float((ub >> 9) | 0x3f800000u) - 1.0f;
            const uint32_t k0 = (i == 0) ? K.kn0[0] : K.kn1[0];
            const uint32_t k1 = (i == 0) ? K.kn0[1] : K.kn1[1];
            const int spike0 = (t < D) ? 1 : 0;
            count += noise_spike_exact(k0, k1, j, p, u) - spike0;
          }
        }
      }
    }
  }

  __syncthreads();
  const int cnt = min(s_cnt, CAP);

  // Batch-resolve borderline draws (expected ~28 per block -> 1 partial wave)
  for (int base = 0; base < cnt; base += 256) {
    const int idx = base + tid;
    if (idx < cnt) {
#pragma clang fp contract(off)
      const uint32_t ow = s_owner[idx];
      const int otid = (int)(ow >> 4);
      const int d = (int)(ow & 15u);
      const int i = d >= 5 ? 1 : 0;
      const int s = d - i * 5;
      const int oo = blockIdx.x * 256 + otid;
      const float po = rates[oo] * 1e-4f;    // same rounding as main loop
      const uint32_t ub = s_ub[idx];
      const float u = __uint_as_float((ub >> 9) | 0x3f800000u) - 1.0f;
      const uint32_t j = (uint32_t)oo + (uint32_t)s * (uint32_t)n;
      const uint32_t k0 = (i == 0) ? K.kn0[0] : K.kn1[0];
      const uint32_t k1 = (i == 0) ? K.kn0[1] : K.kn1[1];
      const int spike = noise_spike_exact(k0, k1, j, po, u);
      const int spike0 = (u < po) ? 1 : 0;   // == main-loop integer decision
      const int delta = spike - spike0;
      if (delta != 0) atomicAdd(&s_delta[otid], delta);
    }
  }

  __syncthreads();
  if (o < n) out[o] = (float)(count + s_delta[tid]);
}

extern "C" void kernel_launch(void* const* d_in, const int* in_sizes, int n_in,
                              void* d_out, int out_size, void* d_ws, size_t ws_size,
                              hipStream_t stream) {
  (void)in_sizes; (void)n_in; (void)d_ws; (void)ws_size;
  const float* rates = (const float*)d_in[0];
  float* out = (float*)d_out;
  const int n = out_size;                      // 8*50*10000*2 = 8,000,000

  // Host-side key derivation (pure arithmetic, graph-capture safe).
  // base key = (0, 42) from jax.random.key(42)
  Keys K;
  for (int i = 0; i < 2; ++i) {
    uint32_t f0, f1;
    tf2x32(0u, 42u, 0u, (uint32_t)i, f0, f1);  // fold_in(key, i)
    uint32_t a0, a1, c0, c1;
    tf2x32(f0, f1, 0u, 0u, a0, a1);            // split -> kn (foldlike)
    tf2x32(f0, f1, 0u, 1u, c0, c1);            // split -> ku
    if (i == 0) { K.kn0[0]=a0; K.kn0[1]=a1; K.ku0[0]=c0; K.ku0[1]=c1; }
    else        { K.kn1[0]=a0; K.kn1[1]=a1; K.ku1[0]=c0; K.ku1[1]=c1; }
  }

  const int grid = (n + 255) / 256;
  hipLaunchKernelGGL(spike_kernel, dim3(grid), dim3(256), 0, stream,
                     rates, out, K, n);
}

// Round 5
// 164.020 us; speedup vs baseline: 1.0080x; 1.0080x over previous
//
#include <hip/hip_runtime.h>
#include <stdint.h>
#include <math.h>

// ===========================================================================
// LegacySpikeGeneratorBinomial — exact JAX threefry2x32 replication.
// Round 5: force 5-way ILP in the hot loop. The five same-key draws are
// computed as manually interleaved independent threefry chains (x0[5]/x1[5],
// fully unrolled static indexing -> registers). Everything else (integer
// decision, LDS compaction queue, exact cold path) unchanged from R4.
// ===========================================================================

#if defined(__HIP_DEVICE_COMPILE__)
#define ROTL32(x, r) __builtin_amdgcn_alignbit((x), (x), 32 - (r))
#else
#define ROTL32(x, r) (((x) << (r)) | ((x) >> (32 - (r))))
#endif

#define TF_R(r) { x0 += x1; x1 = ROTL32(x1, (r)); x1 ^= x0; }

static __host__ __device__ __forceinline__ void tf2x32(
    uint32_t k0, uint32_t k1, uint32_t x0, uint32_t x1,
    uint32_t& o0, uint32_t& o1) {
  const uint32_t ks2 = k0 ^ k1 ^ 0x1BD11BDAu;
  x0 += k0; x1 += k1;
  TF_R(13) TF_R(15) TF_R(26) TF_R(6)
  x0 += k1; x1 += ks2 + 1u;
  TF_R(17) TF_R(29) TF_R(16) TF_R(24)
  x0 += ks2; x1 += k0 + 2u;
  TF_R(13) TF_R(15) TF_R(26) TF_R(6)
  x0 += k0; x1 += k1 + 3u;
  TF_R(17) TF_R(29) TF_R(16) TF_R(24)
  x0 += k1; x1 += ks2 + 4u;
  TF_R(13) TF_R(15) TF_R(26) TF_R(6)
  x0 += ks2; x1 += k0 + 5u;
  o0 = x0; o1 = x1;
}

// Five interleaved threefry chains, same key, counters (0, j0 + s*dn).
#define TF5_R(r)                                              \
  _Pragma("unroll")                                           \
  for (int s = 0; s < 5; ++s) {                               \
    x0[s] += x1[s];                                           \
    x1[s] = ROTL32(x1[s], (r));                               \
    x1[s] ^= x0[s];                                           \
  }
#define TF5_INJ(a, b)                                         \
  _Pragma("unroll")                                           \
  for (int s = 0; s < 5; ++s) { x0[s] += (a); x1[s] += (b); }

__device__ __forceinline__ void tf2x32_x5(
    uint32_t k0, uint32_t k1, uint32_t j0, uint32_t dn,
    uint32_t* ub /*[5]*/) {
  const uint32_t ks2 = k0 ^ k1 ^ 0x1BD11BDAu;
  uint32_t x0[5], x1[5];
#pragma unroll
  for (int s = 0; s < 5; ++s) {
    x0[s] = k0;                          // 0 + k0 (SGPR const)
    x1[s] = j0 + ((uint32_t)s * dn + k1); // per-s SGPR const folded
  }
  TF5_R(13) TF5_R(15) TF5_R(26) TF5_R(6)
  TF5_INJ(k1, ks2 + 1u)
  TF5_R(17) TF5_R(29) TF5_R(16) TF5_R(24)
  TF5_INJ(ks2, k0 + 2u)
  TF5_R(13) TF5_R(15) TF5_R(26) TF5_R(6)
  TF5_INJ(k0, k1 + 3u)
  TF5_R(17) TF5_R(29) TF5_R(16) TF5_R(24)
  TF5_INJ(k1, ks2 + 4u)
  TF5_R(13) TF5_R(15) TF5_R(26) TF5_R(6)
#pragma unroll
  for (int s = 0; s < 5; ++s)
    ub[s] = (x0[s] + ks2) ^ (x1[s] + (k0 + 5u));
}

// XLA erf_inv f32 Giles polynomial, given w = -log1p(-x*x).
__device__ __forceinline__ float erfinv_poly(float w, float x) {
#pragma clang fp contract(off)
  float pp;
  if (w < 5.0f) {
    const float ww = w - 2.5f;
    pp = 2.81022636e-08f;
    pp = 3.43273939e-07f  + pp * ww;
    pp = -3.5233877e-06f  + pp * ww;
    pp = -4.39150654e-06f + pp * ww;
    pp = 0.00021858087f   + pp * ww;
    pp = -0.00125372503f  + pp * ww;
    pp = -0.00417768164f  + pp * ww;
    pp = 0.246640727f     + pp * ww;
    pp = 1.50140941f      + pp * ww;
  } else {
    const float ww = sqrtf(w) - 3.0f;
    pp = -0.000200214257f;
    pp = 0.000100950558f  + pp * ww;
    pp = 0.00134934322f   + pp * ww;
    pp = -0.00367342844f  + pp * ww;
    pp = 0.00573950773f   + pp * ww;
    pp = -0.0076224613f   + pp * ww;
    pp = 0.00943887047f   + pp * ww;
    pp = 1.00167406f      + pp * ww;
    pp = 2.83297682f      + pp * ww;
  }
  return pp * x;
}

struct Keys {
  uint32_t kn0[2], ku0[2], kn1[2], ku1[2];   // per-step noise/uniform keys
};

// Exact XLA chain: noise draw at counter j with key (k0,k1), decide spike.
__device__ __forceinline__ int noise_spike_exact(
    uint32_t k0, uint32_t k1, uint32_t j, float p, float u) {
#pragma clang fp contract(off)
  uint32_t n1, n2;
  tf2x32(k0, k1, 0u, j, n1, n2);
  const uint32_t nb = n1 ^ n2;
  const float f = __uint_as_float((nb >> 9) | 0x3f800000u) - 1.0f;
  // uniform(lo=-0x1.fffffep-1, hi=1): (hi-lo) folds to exactly 2.0f;
  // lax.max(lo, .) is a no-op since f*2 >= 0.
  const float x = f * 2.0f + (-0x1.fffffep-1f);
  const float xx = x * x;
  const float v = -xx;                       // log1p argument, in (-1, 0]
  float we;
  if (fabsf(v) < 1e-4f) {
    we = -((-0.5f * v + 1.0f) * v);          // XLA EmitLog1p small path
  } else {
    const float arg = v + 1.0f;              // f32-round first (FAdd)
    we = -(float)log((double)arg);           // ~CR f32 log
  }
  const float ze = erfinv_poly(we, x);
  const float nz = 1e-3f * (0x1.6a09e6p+0f * ze);  // stddev * sqrt2 * erfinv
  const float t = (p + nz) - u;              // Add then Sub, no FMA
  return t > 0.0f ? 1 : 0;                   // max(sign(t),0)
}

#define CAP 512
#define BORDER_W 90599u   // ceil(2*0.0054*2^23)+2, conservative

__global__ __launch_bounds__(256) void spike_kernel(
    const float* __restrict__ rates, float* __restrict__ out,
    Keys K, int n) {
  __shared__ int s_cnt;
  __shared__ uint32_t s_ub[CAP];
  __shared__ uint32_t s_owner[CAP];          // (tid << 4) | draw_id
  __shared__ int s_delta[256];

  const int tid = threadIdx.x;
  const int o = blockIdx.x * 256 + tid;

  s_delta[tid] = 0;
  if (tid == 0) s_cnt = 0;
  __syncthreads();

  // Per-element integer decision constants.
  int Mlo = 0, D = 0;
  if (o < n) {
#pragma clang fp contract(off)
    const float p = rates[o] * 1e-4f;                 // f32(1/10000) mul
    const int P = (int)ceilf(p * 8388608.0f);         // exact: *2^23 is exp shift
    Mlo = (int)floorf((p - 0.0054f) * 8388608.0f);    // conservative low edge
    D = P - Mlo;                                      // spike0 <=> t < D
  }

  int count = 0;
  if (o < n) {
#pragma unroll
    for (int i = 0; i < 2; ++i) {
      const uint32_t kuk0 = (i == 0) ? K.ku0[0] : K.ku1[0];
      const uint32_t kuk1 = (i == 0) ? K.ku0[1] : K.ku1[1];

      uint32_t ub5[5];
      tf2x32_x5(kuk0, kuk1, (uint32_t)o, (uint32_t)n, ub5);

#pragma unroll
      for (int s = 0; s < 5; ++s) {
        const int d = i * 5 + s;             // draw id 0..9
        const uint32_t ub = ub5[s];
        const int m = (int)(ub >> 9);        // u = m * 2^-23 exactly
        const int t = m - Mlo;
        count += (t < D) ? 1 : 0;            // spike0 = u < p

        if ((uint32_t)t < BORDER_W) {        // |u-p| possibly < max|noise|
          const int slot = atomicAdd(&s_cnt, 1);
          if (slot < CAP) {
            s_ub[slot] = ub;
            s_owner[slot] = ((uint32_t)tid << 4) | (uint32_t)d;
          } else {
            // overflow fallback (statistically unreachable): exact inline
#pragma clang fp contract(off)
            const float p = rates[o] * 1e-4f;
            const float u =
                __uint_as_float((ub >> 9) | 0x3f800000u) - 1.0f;
            const uint32_t j = (uint32_t)o + (uint32_t)s * (uint32_t)n;
            const uint32_t k0 = (i == 0) ? K.kn0[0] : K.kn1[0];
            const uint32_t k1 = (i == 0) ? K.kn0[1] : K.kn1[1];
            const int spike0 = (t < D) ? 1 : 0;
            count += noise_spike_exact(k0, k1, j, p, u) - spike0;
          }
        }
      }
    }
  }

  __syncthreads();
  const int cnt = min(s_cnt, CAP);

  // Batch-resolve borderline draws (expected ~28 per block -> 1 partial wave)
  for (int base = 0; base < cnt; base += 256) {
    const int idx = base + tid;
    if (idx < cnt) {
#pragma clang fp contract(off)
      const uint32_t ow = s_owner[idx];
      const int otid = (int)(ow >> 4);
      const int d = (int)(ow & 15u);
      const int i = d >= 5 ? 1 : 0;
      const int s = d - i * 5;
      const int oo = blockIdx.x * 256 + otid;
      const float po = rates[oo] * 1e-4f;    // same rounding as main loop
      const uint32_t ub = s_ub[idx];
      const float u = __uint_as_float((ub >> 9) | 0x3f800000u) - 1.0f;
      const uint32_t j = (uint32_t)oo + (uint32_t)s * (uint32_t)n;
      const uint32_t k0 = (i == 0) ? K.kn0[0] : K.kn1[0];
      const uint32_t k1 = (i == 0) ? K.kn0[1] : K.kn1[1];
      const int spike = noise_spike_exact(k0, k1, j, po, u);
      const int spike0 = (u < po) ? 1 : 0;   // == main-loop integer decision
      const int delta = spike - spike0;
      if (delta != 0) atomicAdd(&s_delta[otid], delta);
    }
  }

  __syncthreads();
  if (o < n) out[o] = (float)(count + s_delta[tid]);
}

extern "C" void kernel_launch(void* const* d_in, const int* in_sizes, int n_in,
                              void* d_out, int out_size, void* d_ws, size_t ws_size,
                              hipStream_t stream) {
  (void)in_sizes; (void)n_in; (void)d_ws; (void)ws_size;
  const float* rates = (const float*)d_in[0];
  float* out = (float*)d_out;
  const int n = out_size;                      // 8*50*10000*2 = 8,000,000

  // Host-side key derivation (pure arithmetic, graph-capture safe).
  // base key = (0, 42) from jax.random.key(42)
  Keys K;
  for (int i = 0; i < 2; ++i) {
    uint32_t f0, f1;
    tf2x32(0u, 42u, 0u, (uint32_t)i, f0, f1);  // fold_in(key, i)
    uint32_t a0, a1, c0, c1;
    tf2x32(f0, f1, 0u, 0u, a0, a1);            // split -> kn (foldlike)
    tf2x32(f0, f1, 0u, 1u, c0, c1);            // split -> ku
    if (i == 0) { K.kn0[0]=a0; K.kn0[1]=a1; K.ku0[0]=c0; K.ku0[1]=c1; }
    else        { K.kn1[0]=a0; K.kn1[1]=a1; K.ku1[0]=c0; K.ku1[1]=c1; }
  }

  const int grid = (n + 255) / 256;
  hipLaunchKernelGGL(spike_kernel, dim3(grid), dim3(256), 0, stream,
                     rates, out, K, n);
}